// Round 3
// baseline (15.957 us; speedup 1.0000x reference)
//
#include <hip/hip_runtime.h>

#define QN 64
#define PATCH 32
#define HH 512
#define WW 512
#define NPIX (4 * 512 * 512)

// Fully wave-autonomous: no LDS, no __syncthreads, no cross-wave state.
// Each 64-lane wave owns a 32x8 pixel strip (4 px per lane), redundantly
// sorts the 64 queries of its batch, culls against its strip, composites.
__global__ __launch_bounds__(256) void render_kernel(
    const float* __restrict__ patch,    // [B,Q,32,32]
    const float* __restrict__ centers,  // [B,Q,2]
    const float* __restrict__ depth,    // [B,Q,1]
    const float* __restrict__ sizes,    // [B,Q,2]
    const float* __restrict__ dscale,   // [B,Q,1]
    float* __restrict__ out)            // [identity | depth | occ], each B*H*W
{
#pragma clang fp contract(off)
    const int tid  = threadIdx.x;
    const int lane = tid & 63;
    const int wv   = tid >> 6;                  // wave 0..3 -> 8-row strip
    const int b    = blockIdx.z;
    const int tx0  = blockIdx.x << 5;           // 32x32 tile per block
    const int ty0  = blockIdx.y << 5;
    const int xp   = tx0 + ((lane & 7) << 2);   // 4 consecutive x per lane
    const int y    = ty0 + (wv << 3) + (lane >> 3);

    const float STEP = 2.0f / 511.0f;

    // ---- per-lane query params (query index == lane) ----
    const int gi = (b << 6) + lane;
    const float  d  = depth[gi];
    const float2 c2 = ((const float2*)centers)[gi];
    const float2 s2 = ((const float2*)sizes)[gi];

    // mean(depth_scale): butterfly sum, permutation-invariant
    float v = dscale[gi];
#pragma unroll
    for (int off = 32; off; off >>= 1) v += __shfl_xor(v, off);
    const float sm = v * (1.0f / 64.0f);

    // ---- stable descending-depth rank (in-register, no LDS) ----
    int rank = 0;
#pragma unroll
    for (int j = 0; j < QN; ++j) {
        const float dj = __shfl(d, j);
        rank += ((dj > d) || ((dj == d) && (j < lane))) ? 1 : 0;
    }

    // ---- push-permute params into rank space: lane r holds rank-r query ----
    const int addr = rank << 2;
    const float scx = __int_as_float(__builtin_amdgcn_ds_permute(addr, __float_as_int(c2.x)));
    const float scy = __int_as_float(__builtin_amdgcn_ds_permute(addr, __float_as_int(c2.y)));
    const float ssx = __int_as_float(__builtin_amdgcn_ds_permute(addr, __float_as_int(s2.x)));
    const float ssy = __int_as_float(__builtin_amdgcn_ds_permute(addr, __float_as_int(s2.y)));
    const float sd  = __int_as_float(__builtin_amdgcn_ds_permute(addr, __float_as_int(d)));
    const int   spq = __builtin_amdgcn_ds_permute(addr, lane);   // original query idx

    // ---- cull against this wave's 32x8 strip (exact-zero outside C*s) ----
    // sample is exactly 0 when |lx| >= 1 + 1/15.5 = 1.064516..; 1.0660 conservative
    const float C = 1.0660f;
    const float gx_lo = -1.0f + (float)tx0 * STEP;
    const float gx_hi = -1.0f + (float)(tx0 + 31) * STEP;
    const float gy_lo = -1.0f + (float)(ty0 + (wv << 3)) * STEP;
    const float gy_hi = -1.0f + (float)(ty0 + (wv << 3) + 7) * STEP;
    const bool keep = (scx + C * ssx >= gx_lo) && (scx - C * ssx <= gx_hi) &&
                      (scy + C * ssy >= gy_lo) && (scy - C * ssy <= gy_hi);
    unsigned long long m = __ballot(keep);      // lane index == rank -> bit order == depth order

    // ---- composite front-to-back over kept queries ----
    const float gy = -1.0f + (float)y * STEP;
    float gx[4];
#pragma unroll
    for (int k = 0; k < 4; ++k) gx[k] = -1.0f + (float)(xp + k) * STEP;

    float tr[4]  = {1.0f, 1.0f, 1.0f, 1.0f};
    float dp[4]  = {0.0f, 0.0f, 0.0f, 0.0f};
    float idv[4] = {0.0f, 0.0f, 0.0f, 0.0f};
    int hitm = 0;

    while (m) {
        const int i = (int)__builtin_ctzll(m);  // wave-uniform
        m &= m - 1;
        const float cx  = __shfl(scx, i);
        const float cy  = __shfl(scy, i);
        const float sxv = __shfl(ssx, i);
        const float syv = __shfl(ssy, i);
        const float dq  = __shfl(sd,  i);
        const int   pq  = __shfl(spq, i);
        const float iv  = (float)(pq + 1);
        const float* pp = patch + (((size_t)((b << 6) + pq)) << 10);

        // row math shared across the lane's 4 pixels (same y)
        float ly = (gy - cy) / syv;
        ly = fminf(fmaxf(ly, -1.1f), 1.1f);
        const float iy  = (ly + 1.0f) * 0.5f * 31.0f;
        const float y0f = floorf(iy);
        const float wy  = iy - y0f;
        const int   yi  = (int)y0f;
        const bool yok0 = (yi >= 0) && (yi < PATCH);
        const bool yok1 = (yi + 1 >= 0) && (yi + 1 < PATCH);
        const int row0 = yi << 5, row1 = (yi + 1) << 5;

#pragma unroll
        for (int k = 0; k < 4; ++k) {
            float lx = (gx[k] - cx) / sxv;
            lx = fminf(fmaxf(lx, -1.1f), 1.1f);
            const float ixf = (lx + 1.0f) * 0.5f * 31.0f;
            const float x0f = floorf(ixf);
            const float wx  = ixf - x0f;
            const int   xi  = (int)x0f;
            const bool xok0 = (xi >= 0) && (xi < PATCH);
            const bool xok1 = (xi + 1 >= 0) && (xi + 1 < PATCH);
            const float v00 = (xok0 && yok0) ? pp[row0 + xi] : 0.0f;
            const float v01 = (xok1 && yok0) ? pp[row0 + xi + 1] : 0.0f;
            const float v10 = (xok0 && yok1) ? pp[row1 + xi] : 0.0f;
            const float v11 = (xok1 && yok1) ? pp[row1 + xi + 1] : 0.0f;

            const float a = v00 * (1.0f - wx) * (1.0f - wy)
                          + v01 * wx * (1.0f - wy)
                          + v10 * (1.0f - wx) * wy
                          + v11 * wx * wy;

            const float contrib = a * tr[k];
            if (!(hitm & (1 << k)) && (contrib > 0.001f)) { hitm |= (1 << k); idv[k] = iv; }
            dp[k] += contrib * dq;
            tr[k] *= (1.0f - a);
        }
    }

    float4 o_id, o_dp, o_oc;
#pragma unroll
    for (int k = 0; k < 4; ++k) {
        float occ = 1.0f - tr[k];
        occ = fminf(fmaxf(occ, 0.0f), 1.0f);
        const float vis = (occ > 0.05f) ? 1.0f : 0.0f;
        ((float*)&o_id)[k] = idv[k] * vis;
        ((float*)&o_dp)[k] = (dp[k] * vis) * sm;
        ((float*)&o_oc)[k] = occ;
    }

    const size_t pix = ((size_t)b * HH + (size_t)y) * WW + (size_t)xp;
    *(float4*)(out + pix)                    = o_id;
    *(float4*)(out + (size_t)NPIX + pix)     = o_dp;
    *(float4*)(out + 2 * (size_t)NPIX + pix) = o_oc;
}

extern "C" void kernel_launch(void* const* d_in, const int* in_sizes, int n_in,
                              void* d_out, int out_size, void* d_ws, size_t ws_size,
                              hipStream_t stream) {
    const float* patch   = (const float*)d_in[0];
    const float* centers = (const float*)d_in[1];
    const float* depth   = (const float*)d_in[2];
    const float* sizes   = (const float*)d_in[3];
    const float* dscale  = (const float*)d_in[4];
    float* out = (float*)d_out;

    dim3 grid(WW / 32, HH / 32, 4);
    render_kernel<<<grid, 256, 0, stream>>>(patch, centers, depth, sizes, dscale, out);
}